// Round 10
// baseline (801.496 us; speedup 1.0000x reference)
//
#include <hip/hip_runtime.h>
#include <hip/hip_bf16.h>

#define N_POINTS   2000000
#define NUM_GRAPHS 16384
#define HID        40
#define SLOPE      0.01f

// Pass A tiling: 256 pts/block, 1 pt/thread (R5-proven healthy)
#define TILE_A     256
#define NT_A       ((N_POINTS + TILE_A - 1) / TILE_A)   // 7813
#define XESA       288    // dwords per xeT channel row

// Graph-owned back half: 1024 blocks x 4 waves x 4 graphs = 16384 graphs
#define NB    1024
#define GPW   4
#define AROW  20     // dwords per bf16 h1 row (40 bf16)

// LEDGER (cross-round, do not relearn):
//  - PHANTOM-TRAFFIC DISEASE, refined R9: the STREAMED-ACCUMULATOR emb body
//    (runtime j-loop, `s5[c] += h * W2T[c][j]`) correlates with GB-scale
//    FETCH/WRITE in EVERY kernel that contains it (R1,R3 hot; R6,R7,R9 even as
//    a DEAD cold branch). The h[40] + unrolled-j4 form is clean in every host
//    kernel (R0,R2,R4,R5 incl. alongside MFMA at VGPR=64). Dead-branch register
//    pressure is compile-time. FIX: only ever use the h[40]/j4 body.
//    CANARY: WRITE_SIZE >> real stores.
//  - R2: pooled atomics need temporally-clustered issue or L2 write-combining
//    dies (WRITE 21->303MB). Moot here (dense pool, no atomics).
//  - R4: register prefetch of batch/xe = neutral; front-end latency not exposed.
//  - R8: container failure (no data). R9: isolates streamed-body as the poison.

typedef __attribute__((ext_vector_type(8))) short short8;
typedef __attribute__((ext_vector_type(4))) float fx4;

__device__ __forceinline__ float lrelu(float v) { return v > 0.f ? v : SLOPE * v; }
__device__ __forceinline__ int padidx(int p) { return p + ((p >> 5) << 2); }
__device__ __forceinline__ unsigned short f2bf(float f) {
    __hip_bfloat16 h = __float2bfloat16(f);
    return *(unsigned short*)&h;
}
__device__ __forceinline__ float bf2f(unsigned short u) {
    unsigned int v = ((unsigned int)u) << 16;
    return __uint_as_float(v);
}

// ---------------- starts: start[g] = first i with batch[i] >= g; start[B] = N ----------------
__global__ __launch_bounds__(256) void k_starts(
    const int* __restrict__ batch, int* __restrict__ start)
{
    int i = blockIdx.x * 256 + threadIdx.x;
    if (i >= N_POINTS) return;
    int b = batch[i];
    if (i == 0) {
        for (int g = 0; g <= b; ++g) start[g] = 0;
    } else {
        int bp = batch[i - 1];
        for (int g = bp + 1; g <= b; ++g) start[g] = i;
    }
    if (i == N_POINTS - 1) {
        for (int g = b + 1; g <= NUM_GRAPHS; ++g) start[g] = N_POINTS;
    }
}

// ---------------- Pass A: emb FFN (1 pt/thread) + transpose-reduce + xe bf16 cache ----------------
// R5-proven verbatim.
__global__ __launch_bounds__(256, 4) void k_emb_aggr(
    const float* __restrict__ x, const int* __restrict__ batch,
    const float* __restrict__ We1, const float* __restrict__ We2,
    float* __restrict__ x_aggr, unsigned short* __restrict__ xe_out, int use_xe)
{
    __shared__ __align__(16) float sWe1[3 * HID];
    __shared__ __align__(16) float sWe2T[5 * HID];          // [c][j]
    __shared__ __align__(16) float xeT[5 * XESA];           // chunk-padded
    __shared__ __align__(16) int   sbp[XESA];

    int tid = threadIdx.x;
    for (int k = tid; k < 3 * HID; k += 256) sWe1[k] = We1[k];
    for (int k = tid; k < 5 * HID; k += 256) sWe2T[k] = We2[(k % HID) * 5 + k / HID];
    __syncthreads();

    int p = blockIdx.x * TILE_A + tid;
    bool v = p < N_POINTS;
    int ic = v ? p : (N_POINTS - 1);
    float x0 = x[ic * 3 + 0], x1 = x[ic * 3 + 1], x2 = x[ic * 3 + 2];
    int b = v ? batch[ic] : -1;
    sbp[padidx(tid)] = b;

    float h[HID];
    const float4* W1r = (const float4*)sWe1;
#pragma unroll
    for (int j4 = 0; j4 < HID / 4; ++j4) {
        float4 wa = W1r[j4], wb = W1r[10 + j4], wc = W1r[20 + j4];
        float wav[4] = {wa.x, wa.y, wa.z, wa.w};
        float wbv[4] = {wb.x, wb.y, wb.z, wb.w};
        float wcv[4] = {wc.x, wc.y, wc.z, wc.w};
#pragma unroll
        for (int k = 0; k < 4; ++k)
            h[j4 * 4 + k] = lrelu(x0 * wav[k] + x1 * wbv[k] + x2 * wcv[k]);
    }

#pragma unroll
    for (int c = 0; c < 5; ++c) {
        const float4* wr = (const float4*)&sWe2T[c * HID];
        float s = 0.f;
#pragma unroll
        for (int j4 = 0; j4 < HID / 4; ++j4) {
            float4 w = wr[j4];
            s += h[j4 * 4 + 0] * w.x + h[j4 * 4 + 1] * w.y + h[j4 * 4 + 2] * w.z + h[j4 * 4 + 3] * w.w;
        }
        float e = v ? lrelu(s) : 0.f;
        xeT[c * XESA + padidx(tid)] = e;
        if (use_xe && v) xe_out[(size_t)c * N_POINTS + p] = f2bf(e);
    }
    __syncthreads();

    if (tid < 40) {
        int ch = tid >> 3, chunk = tid & 7;
        float acc = 0.f;
        int cur = sbp[chunk * 36];
#pragma unroll
        for (int g = 0; g < 8; ++g) {
            float4 v4 = *(const float4*)&xeT[ch * XESA + chunk * 36 + g * 4];
            int4   n4 = *(const int4*)&sbp[chunk * 36 + g * 4];
            float vv[4] = {v4.x, v4.y, v4.z, v4.w};
            int   nn[4] = {n4.x, n4.y, n4.z, n4.w};
#pragma unroll
            for (int k = 0; k < 4; ++k) {
                if (nn[k] != cur) {
                    if (cur >= 0) atomicAdd(&x_aggr[cur * 5 + ch], acc);
                    cur = nn[k];
                    acc = vv[k];
                } else {
                    acc += vv[k];
                }
            }
        }
        if (cur >= 0) atomicAdd(&x_aggr[cur * 5 + ch], acc);
    }
}

// ---------------- Pass B: per-graph global FFN + fold into W_out1 rows 5..8 ----------------
__global__ __launch_bounds__(256) void k_global(
    const float* __restrict__ x_aggr,
    const float* __restrict__ Wg1, const float* __restrict__ Wg2,
    const float* __restrict__ Wo1,
    float* __restrict__ g_contrib)
{
    __shared__ float sWg1[5 * HID];
    __shared__ float sWg2[HID * 4];
    __shared__ float sWo1g[4 * HID];
    for (int k = threadIdx.x; k < 5 * HID; k += 256) sWg1[k] = Wg1[k];
    for (int k = threadIdx.x; k < HID * 4; k += 256) sWg2[k] = Wg2[k];
    for (int k = threadIdx.x; k < 4 * HID; k += 256) sWo1g[k] = Wo1[5 * HID + k];
    __syncthreads();

    int bg = blockIdx.x * 256 + threadIdx.x;
    if (bg >= NUM_GRAPHS) return;

    float a[5];
#pragma unroll
    for (int c = 0; c < 5; ++c) a[c] = x_aggr[bg * 5 + c];

    float h[HID];
#pragma unroll
    for (int j = 0; j < HID; ++j) {
        float s = 0.f;
#pragma unroll
        for (int c = 0; c < 5; ++c) s += a[c] * sWg1[c * HID + j];
        h[j] = lrelu(s);
    }
    float g[4];
#pragma unroll
    for (int c = 0; c < 4; ++c) {
        float s = 0.f;
#pragma unroll
        for (int j = 0; j < HID; ++j) s += h[j] * sWg2[j * 4 + c];
        g[c] = lrelu(s);
    }
#pragma unroll
    for (int j = 0; j < HID; ++j) {
        float s = 0.f;
#pragma unroll
        for (int c = 0; c < 4; ++c) s += g[c] * sWo1g[c * HID + j];
        g_contrib[bg * HID + j] = s;
    }
}

// ---------------- Pass C': graph-owned out-FFN + dense pool + disc head ----------------
// Single change vs R9: cold fallback replaced with the PROVEN h[40]/j4-unrolled
// emb body (clean alongside MFMA in R5's k_out_pool). The streamed-accumulator
// form is banned per LEDGER (phantom-traffic poison even as dead code).
__global__ __launch_bounds__(256, 4) void k_out_disc(
    const int* __restrict__ start,
    const float* __restrict__ x,
    const float* __restrict__ We1, const float* __restrict__ We2,
    const float* __restrict__ Wo1, const float* __restrict__ Wo2,
    const float* __restrict__ Wd1, const float* __restrict__ Wd2,
    const float* __restrict__ g_contrib,
    const unsigned short* __restrict__ xe_in, int use_xe,
    float* __restrict__ out)
{
    __shared__ __align__(16) float sWo1[5 * HID];
    __shared__ __align__(16) float sWd1T[HID * 32];     // [j][c]
    __shared__ __align__(16) float sWd2[HID];
    __shared__ __align__(16) float sWe1[3 * HID];       // cold path only
    __shared__ __align__(16) float sWe2T[5 * HID];      // cold path only
    __shared__ __align__(16) float pld[4][32];
    __shared__ __align__(16) unsigned int h1S[4][64 * AROW];

    int tid = threadIdx.x;
    for (int k = tid; k < 5 * HID; k += 256) sWo1[k] = Wo1[k];
    for (int k = tid; k < 32 * HID; k += 256) sWd1T[k] = Wd1[(k % 32) * HID + k / 32];
    for (int k = tid; k < HID; k += 256) sWd2[k] = Wd2[k];
    for (int k = tid; k < 3 * HID; k += 256) sWe1[k] = We1[k];
    for (int k = tid; k < 5 * HID; k += 256) sWe2T[k] = We2[(k % HID) * 5 + k / HID];

    int wid = tid >> 6, lane = tid & 63;
    int l16 = lane & 15, quad = lane >> 4;

    // B fragments (Wo2 -> bf16), proven layout, built once
    short8 bfrag[2][2];
#pragma unroll
    for (int nt = 0; nt < 2; ++nt) {
#pragma unroll
        for (int ks = 0; ks < 2; ++ks) {
#pragma unroll
            for (int j = 0; j < 8; ++j) {
                int kk = ks * 32 + quad * 8 + j;
                float w = (kk < HID) ? Wo2[kk * 32 + nt * 16 + l16] : 0.f;
                bfrag[nt][ks][j] = (short)f2bf(w);
            }
        }
    }
    short8 zfrag = {0, 0, 0, 0, 0, 0, 0, 0};
    __syncthreads();   // weights visible; waves independent hereafter

    int wslot = blockIdx.x * 4 + wid;

    for (int gi = 0; gi < GPW; ++gi) {
        int g = wslot * GPW + gi;
        int sg = start[g], eg = start[g + 1];
        int nr = (eg - sg + 63) >> 6;

        const float4* gc4 = (const float4*)(g_contrib + (size_t)g * HID);  // wave-uniform
        float gpool[2] = {0.f, 0.f};

        for (int r = 0; r < nr; ++r) {
            int idx = sg + r * 64 + lane;
            bool v = idx < eg;
            int ic = v ? idx : sg;

            float xe[5];
            if (use_xe) {
#pragma unroll
                for (int c = 0; c < 5; ++c) xe[c] = bf2f(xe_in[(size_t)c * N_POINTS + ic]);
            } else {
                // cold fallback: PROVEN h[40]/j4 body (R5 k_out_pool verbatim)
                float x0 = x[ic * 3 + 0], x1 = x[ic * 3 + 1], x2 = x[ic * 3 + 2];
                float h[HID];
                const float4* W1r = (const float4*)sWe1;
#pragma unroll
                for (int j4 = 0; j4 < HID / 4; ++j4) {
                    float4 wa = W1r[j4], wb = W1r[10 + j4], wc = W1r[20 + j4];
                    float wav[4] = {wa.x, wa.y, wa.z, wa.w};
                    float wbv[4] = {wb.x, wb.y, wb.z, wb.w};
                    float wcv[4] = {wc.x, wc.y, wc.z, wc.w};
#pragma unroll
                    for (int k = 0; k < 4; ++k)
                        h[j4 * 4 + k] = lrelu(x0 * wav[k] + x1 * wbv[k] + x2 * wcv[k]);
                }
#pragma unroll
                for (int c = 0; c < 5; ++c) {
                    const float4* wr = (const float4*)&sWe2T[c * HID];
                    float s = 0.f;
#pragma unroll
                    for (int j4 = 0; j4 < HID / 4; ++j4) {
                        float4 w = wr[j4];
                        s += h[j4 * 4 + 0] * w.x + h[j4 * 4 + 1] * w.y + h[j4 * 4 + 2] * w.z + h[j4 * 4 + 3] * w.w;
                    }
                    xe[c] = lrelu(s);
                }
            }

            // h1 = lrelu(xe @ Wo1[0:5] + g_contrib[g]); pack bf16; stage (invalid -> 0)
            unsigned int* row = &h1S[wid][lane * AROW];
#pragma unroll
            for (int j4 = 0; j4 < HID / 4; ++j4) {
                float4 gv = gc4[j4];
                float sv[4] = {gv.x, gv.y, gv.z, gv.w};
#pragma unroll
                for (int c = 0; c < 5; ++c) {
                    float4 w = ((const float4*)&sWo1[c * HID])[j4];
                    float wvv[4] = {w.x, w.y, w.z, w.w};
#pragma unroll
                    for (int k = 0; k < 4; ++k) sv[k] += xe[c] * wvv[k];
                }
                __hip_bfloat162 q0 = __float22bfloat162_rn(make_float2(lrelu(sv[0]), lrelu(sv[1])));
                __hip_bfloat162 q1 = __float22bfloat162_rn(make_float2(lrelu(sv[2]), lrelu(sv[3])));
                uint2 u;
                u.x = v ? *(unsigned int*)&q0 : 0u;
                u.y = v ? *(unsigned int*)&q1 : 0u;
                *(uint2*)(row + j4 * 2) = u;
            }

            // MFMA (proven layout): 4 m-tiles x 2 ntiles; K = 32 + 8
#pragma unroll
            for (int m = 0; m < 4; ++m) {
                const unsigned int* arow = &h1S[wid][(m * 16 + l16) * AROW];
                short8 a0 = *(const short8*)(arow + quad * 4);
                short8 a1 = (quad == 0) ? *(const short8*)(arow + 16) : zfrag;
#pragma unroll
                for (int nt = 0; nt < 2; ++nt) {
                    fx4 acc = {0.f, 0.f, 0.f, 0.f};
                    acc = __builtin_amdgcn_mfma_f32_16x16x32_bf16(a0, bfrag[nt][0], acc, 0, 0, 0);
                    acc = __builtin_amdgcn_mfma_f32_16x16x32_bf16(a1, bfrag[nt][1], acc, 0, 0, 0);
                    // C layout: col = l16 = channel; rows = points -> dense pool = sum rows
#pragma unroll
                    for (int rr = 0; rr < 4; ++rr) gpool[nt] += lrelu(acc[rr]);
                }
            }
        }

        // pool over quad groups (lanes sharing l16): 64 pts x all rounds summed
#pragma unroll
        for (int nt = 0; nt < 2; ++nt) {
            gpool[nt] += __shfl_xor(gpool[nt], 16);
            gpool[nt] += __shfl_xor(gpool[nt], 32);
        }
        if (quad == 0) {
            pld[wid][l16] = gpool[0];
            pld[wid][16 + l16] = gpool[1];
        }

        // disc head: lane j<40 -> lrelu(pooled @ Wd1)[j] * Wd2[j], wave-reduce
        float accd = 0.f;
        if (lane < HID) {
            const float4* pp = (const float4*)&pld[wid][0];
            const float4* wr = (const float4*)&sWd1T[lane * 32];
            float s = 0.f;
#pragma unroll
            for (int c4 = 0; c4 < 8; ++c4) {
                float4 w = wr[c4];
                float4 p = pp[c4];
                s += p.x * w.x + p.y * w.y + p.z * w.z + p.w * w.w;
            }
            accd = lrelu(s) * sWd2[lane];
        }
#pragma unroll
        for (int m = 1; m < 64; m <<= 1) accd += __shfl_xor(accd, m);
        if (lane == 0) out[g] = accd;
    }
}

extern "C" void kernel_launch(void* const* d_in, const int* in_sizes, int n_in,
                              void* d_out, int out_size, void* d_ws, size_t ws_size,
                              hipStream_t stream) {
    const float* x     = (const float*)d_in[0];
    const int*   batch = (const int*)  d_in[1];
    const float* We1   = (const float*)d_in[2];
    const float* We2   = (const float*)d_in[3];
    const float* Wg1   = (const float*)d_in[4];
    const float* Wg2   = (const float*)d_in[5];
    const float* Wo1   = (const float*)d_in[6];
    const float* Wo2   = (const float*)d_in[7];
    const float* Wd1   = (const float*)d_in[8];
    const float* Wd2   = (const float*)d_in[9];
    float* out = (float*)d_out;

    // ws layout: [x_aggr B*5][g_contrib B*40][start B+1][xe bf16 planar 5*N]
    float* x_aggr    = (float*)d_ws;
    float* g_contrib = x_aggr + NUM_GRAPHS * 5;
    int*   start     = (int*)(g_contrib + NUM_GRAPHS * HID);
    size_t head_bytes = (size_t)NUM_GRAPHS * (5 + HID) * sizeof(float)
                      + (NUM_GRAPHS + 1) * sizeof(int);
    unsigned short* xe_ws = (unsigned short*)((char*)d_ws + ((head_bytes + 15) & ~(size_t)15));
    size_t need = ((head_bytes + 15) & ~(size_t)15) + (size_t)N_POINTS * 5 * sizeof(unsigned short);
    int use_xe = (ws_size >= need) ? 1 : 0;

    hipMemsetAsync(x_aggr, 0, (size_t)NUM_GRAPHS * 5 * sizeof(float), stream);

    int gblk = (NUM_GRAPHS + 255) / 256;
    k_starts  <<<(N_POINTS + 255) / 256, 256, 0, stream>>>(batch, start);
    k_emb_aggr<<<NT_A, 256, 0, stream>>>(x, batch, We1, We2, x_aggr, xe_ws, use_xe);
    k_global  <<<gblk, 256, 0, stream>>>(x_aggr, Wg1, Wg2, Wo1, g_contrib);
    k_out_disc<<<NB, 256, 0, stream>>>(start, x, We1, We2, Wo1, Wo2, Wd1, Wd2,
                                       g_contrib, xe_ws, use_xe, out);
}

// Round 11
// 198.771 us; speedup vs baseline: 4.0323x; 4.0323x over previous
//
#include <hip/hip_runtime.h>
#include <hip/hip_bf16.h>

#define N_POINTS   2000000
#define NUM_GRAPHS 16384
#define HID        40
#define SLOPE      0.01f

// Pass A tiling: 256 pts/block, 1 pt/thread (R5-proven healthy)
#define TILE_A     256
#define NT_A       ((N_POINTS + TILE_A - 1) / TILE_A)   // 7813
#define XESA       288    // dwords per xeT channel row (8 chunks x 36; padidx max 283)

// Pass C tiling: 256 pts/tile, grid-stride, wave-private regions + ONE barrier/tile
#define TILE       256
#define NTILES     ((N_POINTS + TILE - 1) / TILE)       // 7813
#define AROW       20     // dwords per bf16 A-staging row (40 bf16)
#define XOS        68     // per-wave xoT stride in dwords: [ch][64 pts + 4 pad]
#define WREG       (32 * XOS)   // 2176 dwords = 8704 B per-wave LDS region
#define NB_C       2048   // grid for k_out_pool; grid-stride kernel, host-side-only change vs R5

// LEDGER (cross-round, final):
//  - PHANTOM-TRAFFIC DISEASE (R1,R3,R6,R7,R9,R10): kernels with per-graph
//    variable-trip nested outer loops (graph-owned structure) produce GB-scale
//    scratch-like FETCH/WRITE regardless of which emb-FFN body variant they
//    contain (streamed OR h[40]/j4), at VGPR=64 AND 128. The SAME bodies in the
//    flat grid-stride structure (R0,R2,R4,R5) are clean (FETCH 16MB, WRITE 21MB).
//    Conclusion: outer-loop shape flips codegen into scratch mode; undiagnosable
//    without disasm. DO NOT reintroduce graph-owned loops in this loop.
//  - R2: pooled atomics need temporally-clustered (lockstep) reduce phases or L2
//    write-combining dies (WRITE 21->303MB, dur 62->103us). Keep the per-tile
//    barrier in pass C.
//  - R4: register prefetch of batch/xe = neutral (front-end latency not exposed).
//  - R5 champion: 189.7us total; k_out_pool 61.4us / VGPR 64 / WRITE 20.9MB.
//  - R11 (this): byte-identical device code to R5; k_out_pool grid 1024->2048
//    (host-only, codegen-neutral) for end-of-kernel tail balance.

typedef __attribute__((ext_vector_type(8))) short short8;
typedef __attribute__((ext_vector_type(4))) float fx4;

__device__ __forceinline__ float lrelu(float v) { return v > 0.f ? v : SLOPE * v; }
__device__ __forceinline__ int padidx(int p) { return p + ((p >> 5) << 2); }  // +4 dwords per 32-chunk
__device__ __forceinline__ unsigned short f2bf(float f) {
    __hip_bfloat16 h = __float2bfloat16(f);
    return *(unsigned short*)&h;
}
__device__ __forceinline__ float bf2f(unsigned short u) {
    unsigned int v = ((unsigned int)u) << 16;
    return __uint_as_float(v);
}

// ---------------- Pass A: emb FFN (1 pt/thread, h[40]/j4 body) + transpose-reduce + xe cache ----------------
// R5-proven verbatim.
__global__ __launch_bounds__(256, 4) void k_emb_aggr(
    const float* __restrict__ x, const int* __restrict__ batch,
    const float* __restrict__ We1, const float* __restrict__ We2,
    float* __restrict__ x_aggr, unsigned short* __restrict__ xe_out, int use_xe)
{
    __shared__ __align__(16) float sWe1[3 * HID];
    __shared__ __align__(16) float sWe2T[5 * HID];          // [c][j]
    __shared__ __align__(16) float xeT[5 * XESA];           // chunk-padded
    __shared__ __align__(16) int   sbp[XESA];

    int tid = threadIdx.x;
    for (int k = tid; k < 3 * HID; k += 256) sWe1[k] = We1[k];
    for (int k = tid; k < 5 * HID; k += 256) sWe2T[k] = We2[(k % HID) * 5 + k / HID];
    __syncthreads();

    int p = blockIdx.x * TILE_A + tid;
    bool v = p < N_POINTS;
    int ic = v ? p : (N_POINTS - 1);
    float x0 = x[ic * 3 + 0], x1 = x[ic * 3 + 1], x2 = x[ic * 3 + 2];
    int b = v ? batch[ic] : -1;
    sbp[padidx(tid)] = b;

    float h[HID];
    const float4* W1r = (const float4*)sWe1;
#pragma unroll
    for (int j4 = 0; j4 < HID / 4; ++j4) {
        float4 wa = W1r[j4], wb = W1r[10 + j4], wc = W1r[20 + j4];
        float wav[4] = {wa.x, wa.y, wa.z, wa.w};
        float wbv[4] = {wb.x, wb.y, wb.z, wb.w};
        float wcv[4] = {wc.x, wc.y, wc.z, wc.w};
#pragma unroll
        for (int k = 0; k < 4; ++k)
            h[j4 * 4 + k] = lrelu(x0 * wav[k] + x1 * wbv[k] + x2 * wcv[k]);
    }

#pragma unroll
    for (int c = 0; c < 5; ++c) {
        const float4* wr = (const float4*)&sWe2T[c * HID];
        float s = 0.f;
#pragma unroll
        for (int j4 = 0; j4 < HID / 4; ++j4) {
            float4 w = wr[j4];
            s += h[j4 * 4 + 0] * w.x + h[j4 * 4 + 1] * w.y + h[j4 * 4 + 2] * w.z + h[j4 * 4 + 3] * w.w;
        }
        float e = v ? lrelu(s) : 0.f;
        xeT[c * XESA + padidx(tid)] = e;
        if (use_xe && v) xe_out[(size_t)c * N_POINTS + p] = f2bf(e);
    }
    __syncthreads();

    if (tid < 40) {
        int ch = tid >> 3, chunk = tid & 7;
        float acc = 0.f;
        int cur = sbp[chunk * 36];
#pragma unroll
        for (int g = 0; g < 8; ++g) {
            float4 v4 = *(const float4*)&xeT[ch * XESA + chunk * 36 + g * 4];
            int4   n4 = *(const int4*)&sbp[chunk * 36 + g * 4];
            float vv[4] = {v4.x, v4.y, v4.z, v4.w};
            int   nn[4] = {n4.x, n4.y, n4.z, n4.w};
#pragma unroll
            for (int k = 0; k < 4; ++k) {
                if (nn[k] != cur) {
                    if (cur >= 0) atomicAdd(&x_aggr[cur * 5 + ch], acc);
                    cur = nn[k];
                    acc = vv[k];
                } else {
                    acc += vv[k];
                }
            }
        }
        if (cur >= 0) atomicAdd(&x_aggr[cur * 5 + ch], acc);
    }
}

// ---------------- Pass B: per-graph global FFN + fold into W_out1 rows 5..8 ----------------
__global__ __launch_bounds__(256) void k_global(
    const float* __restrict__ x_aggr,
    const float* __restrict__ Wg1, const float* __restrict__ Wg2,
    const float* __restrict__ Wo1,
    float* __restrict__ g_contrib)
{
    __shared__ float sWg1[5 * HID];
    __shared__ float sWg2[HID * 4];
    __shared__ float sWo1g[4 * HID];
    for (int k = threadIdx.x; k < 5 * HID; k += 256) sWg1[k] = Wg1[k];
    for (int k = threadIdx.x; k < HID * 4; k += 256) sWg2[k] = Wg2[k];
    for (int k = threadIdx.x; k < 4 * HID; k += 256) sWo1g[k] = Wo1[5 * HID + k];
    __syncthreads();

    int bg = blockIdx.x * 256 + threadIdx.x;
    if (bg >= NUM_GRAPHS) return;

    float a[5];
#pragma unroll
    for (int c = 0; c < 5; ++c) a[c] = x_aggr[bg * 5 + c];

    float h[HID];
#pragma unroll
    for (int j = 0; j < HID; ++j) {
        float s = 0.f;
#pragma unroll
        for (int c = 0; c < 5; ++c) s += a[c] * sWg1[c * HID + j];
        h[j] = lrelu(s);
    }
    float g[4];
#pragma unroll
    for (int c = 0; c < 4; ++c) {
        float s = 0.f;
#pragma unroll
        for (int j = 0; j < HID; ++j) s += h[j] * sWg2[j * 4 + c];
        g[c] = lrelu(s);
    }
#pragma unroll
    for (int j = 0; j < HID; ++j) {
        float s = 0.f;
#pragma unroll
        for (int c = 0; c < 4; ++c) s += g[c] * sWo1g[c * HID + j];
        g_contrib[bg * HID + j] = s;
    }
}

// ---------------- Pass C: wave-private LDS regions + ONE barrier per tile ----------------
// R5-proven verbatim. The barrier rate-matches waves so same-line pooled atomics
// stay temporally clustered (R2 lesson: removing it -> WRITE 21->303MB).
__global__ __launch_bounds__(256, 4) void k_out_pool(
    const float* __restrict__ x, const int* __restrict__ batch,
    const float* __restrict__ We1, const float* __restrict__ We2,
    const float* __restrict__ Wo1, const float* __restrict__ Wo2,
    const float* __restrict__ g_contrib,
    const unsigned short* __restrict__ xe_in, int use_xe,
    float* __restrict__ pooled)
{
    // 4 wave-private regions; A-staging (64 rows x 20 dw = 1280 dw) aliases the front
    // of each 2176-dw xoT region; in-wave DS ordering makes the alias safe.
    __shared__ __align__(16) unsigned int uLds[4 * WREG];
    __shared__ __align__(16) int sb[TILE];
    __shared__ float sWe1[3 * HID];
    __shared__ float sWe2T[5 * HID];
    __shared__ float sWo1[5 * HID];

    int tid = threadIdx.x;
    for (int k = tid; k < 3 * HID; k += 256) sWe1[k] = We1[k];
    for (int k = tid; k < 5 * HID; k += 256) sWe2T[k] = We2[(k % HID) * 5 + k / HID];
    for (int k = tid; k < 5 * HID; k += 256) sWo1[k] = Wo1[k];

    int wid = tid >> 6, lane = tid & 63;
    int l16 = lane & 15, quad = lane >> 4;
    unsigned int* wreg = &uLds[wid * WREG];

    // B fragments (Wo2 -> bf16), built once: lane l16 = n, k = ks*32 + quad*8 + j
    short8 bfrag[2][2];
#pragma unroll
    for (int nt = 0; nt < 2; ++nt) {
#pragma unroll
        for (int ks = 0; ks < 2; ++ks) {
#pragma unroll
            for (int j = 0; j < 8; ++j) {
                int kk = ks * 32 + quad * 8 + j;
                float w = (kk < HID) ? Wo2[kk * 32 + nt * 16 + l16] : 0.f;
                bfrag[nt][ks][j] = (short)f2bf(w);
            }
        }
    }
    short8 zfrag = {0, 0, 0, 0, 0, 0, 0, 0};
    __syncthreads();   // weights visible

    for (int t = blockIdx.x; t < NTILES; t += gridDim.x) {
        int i = t * TILE + tid;
        bool v = i < N_POINTS;
        int ic = v ? i : (N_POINTS - 1);
        int b = v ? batch[ic] : -1;
        sb[tid] = b;    // wave-private slice: only own wave reads sb[wid*64..+63]

        float xe[5];
        if (use_xe) {
#pragma unroll
            for (int c = 0; c < 5; ++c) xe[c] = bf2f(xe_in[(size_t)c * N_POINTS + ic]);
        } else {
            float x0 = x[ic * 3 + 0], x1 = x[ic * 3 + 1], x2 = x[ic * 3 + 2];
            float h[HID];
            const float4* W1r = (const float4*)sWe1;
#pragma unroll
            for (int j4 = 0; j4 < HID / 4; ++j4) {
                float4 wa = W1r[j4], wb = W1r[10 + j4], wc = W1r[20 + j4];
                float wav[4] = {wa.x, wa.y, wa.z, wa.w};
                float wbv[4] = {wb.x, wb.y, wb.z, wb.w};
                float wcv[4] = {wc.x, wc.y, wc.z, wc.w};
#pragma unroll
                for (int k = 0; k < 4; ++k)
                    h[j4 * 4 + k] = lrelu(x0 * wav[k] + x1 * wbv[k] + x2 * wcv[k]);
            }
#pragma unroll
            for (int c = 0; c < 5; ++c) {
                const float4* wr = (const float4*)&sWe2T[c * HID];
                float s = 0.f;
#pragma unroll
                for (int j4 = 0; j4 < HID / 4; ++j4) {
                    float4 w = wr[j4];
                    s += h[j4 * 4 + 0] * w.x + h[j4 * 4 + 1] * w.y + h[j4 * 4 + 2] * w.z + h[j4 * 4 + 3] * w.w;
                }
                xe[c] = lrelu(s);
            }
        }

        // h1 = lrelu(xe @ Wo1[0:5] + g_contrib[b]); pack bf16; stage A row (wave-private)
        const float4* gc4 = (const float4*)(g_contrib + (size_t)(b >= 0 ? b : 0) * HID);
        unsigned int* row = &wreg[lane * AROW];
#pragma unroll
        for (int j4 = 0; j4 < HID / 4; ++j4) {
            float4 g = gc4[j4];
            float sv[4] = {g.x, g.y, g.z, g.w};
#pragma unroll
            for (int c = 0; c < 5; ++c) {
                float4 w = ((const float4*)&sWo1[c * HID])[j4];
                float wvv[4] = {w.x, w.y, w.z, w.w};
#pragma unroll
                for (int k = 0; k < 4; ++k) sv[k] += xe[c] * wvv[k];
            }
            __hip_bfloat162 q0 = __float22bfloat162_rn(make_float2(lrelu(sv[0]), lrelu(sv[1])));
            __hip_bfloat162 q1 = __float22bfloat162_rn(make_float2(lrelu(sv[2]), lrelu(sv[3])));
            uint2 u;
            u.x = *(unsigned int*)&q0; u.y = *(unsigned int*)&q1;
            *(uint2*)(row + j4 * 2) = u;
        }

        // MFMA: wave's 4 local m-tiles x 2 ntiles; K = 32 + 8 (second frag zero for quad>0)
        fx4 xov[4][2];
#pragma unroll
        for (int m = 0; m < 4; ++m) {
            const unsigned int* arow = &wreg[(m * 16 + l16) * AROW];
            short8 a0 = *(const short8*)(arow + quad * 4);
            short8 a1 = (quad == 0) ? *(const short8*)(arow + 16) : zfrag;
#pragma unroll
            for (int nt = 0; nt < 2; ++nt) {
                fx4 acc = {0.f, 0.f, 0.f, 0.f};
                acc = __builtin_amdgcn_mfma_f32_16x16x32_bf16(a0, bfrag[nt][0], acc, 0, 0, 0);
                acc = __builtin_amdgcn_mfma_f32_16x16x32_bf16(a1, bfrag[nt][1], acc, 0, 0, 0);
#pragma unroll
                for (int r = 0; r < 4; ++r) acc[r] = lrelu(acc[r]);
                xov[m][nt] = acc;
            }
        }

        // transpose into wave-private xoT [ch][64 pts] (clobbers own staging; in-wave
        // DS ordering guarantees own MFMA reads complete first)
        float* xoT = (float*)wreg;
#pragma unroll
        for (int m = 0; m < 4; ++m) {
#pragma unroll
            for (int nt = 0; nt < 2; ++nt) {
                int ch = nt * 16 + l16;
                *(fx4*)&xoT[ch * XOS + m * 16 + quad * 4] = xov[m][nt];
            }
        }

        // wave-private reduce: lane owns (ch = lane&31, half = lane>>5 of 32 pts)
        {
            int ch = lane & 31, half = lane >> 5;
            int pbase = half * 32;
            const int* sbw = &sb[wid * 64];
            float acc = 0.f;
            int cur = sbw[pbase];
#pragma unroll
            for (int g = 0; g < 8; ++g) {
                float4 v4 = *(const float4*)&xoT[ch * XOS + pbase + g * 4];
                int4   n4 = *(const int4*)&sbw[pbase + g * 4];
                float vv[4] = {v4.x, v4.y, v4.z, v4.w};
                int   nn[4] = {n4.x, n4.y, n4.z, n4.w};
#pragma unroll
                for (int k = 0; k < 4; ++k) {
                    if (nn[k] != cur) {
                        if (cur >= 0) atomicAdd(&pooled[cur * 32 + ch], acc);
                        cur = nn[k];
                        acc = vv[k];
                    } else {
                        acc += vv[k];
                    }
                }
            }
            if (cur >= 0) atomicAdd(&pooled[cur * 32 + ch], acc);
        }

        __syncthreads();   // rate-match waves once per tile (atomic write-combining)
    }
}

// ---------------- Pass D: disc head per graph ----------------
__global__ __launch_bounds__(256) void k_disc(
    const float* __restrict__ pooled,
    const float* __restrict__ Wd1, const float* __restrict__ Wd2,
    float* __restrict__ out)
{
    __shared__ float sWd1T[HID * 32];  // [j][c]
    __shared__ float sWd2[HID];
    for (int k = threadIdx.x; k < 32 * HID; k += 256) sWd1T[k] = Wd1[(k % 32) * HID + k / 32];
    for (int k = threadIdx.x; k < HID; k += 256) sWd2[k] = Wd2[k];
    __syncthreads();

    int bg = blockIdx.x * 256 + threadIdx.x;
    if (bg >= NUM_GRAPHS) return;

    float p[32];
    const float4* pp = (const float4*)(pooled + (size_t)bg * 32);
#pragma unroll
    for (int c4 = 0; c4 < 8; ++c4) {
        float4 vv = pp[c4];
        p[c4 * 4 + 0] = vv.x; p[c4 * 4 + 1] = vv.y; p[c4 * 4 + 2] = vv.z; p[c4 * 4 + 3] = vv.w;
    }

    float acc = 0.f;
#pragma unroll
    for (int j = 0; j < HID; ++j) {
        const float4* wr = (const float4*)&sWd1T[j * 32];
        float s = 0.f;
#pragma unroll
        for (int c4 = 0; c4 < 8; ++c4) {
            float4 w = wr[c4];
            s += p[c4 * 4 + 0] * w.x + p[c4 * 4 + 1] * w.y + p[c4 * 4 + 2] * w.z + p[c4 * 4 + 3] * w.w;
        }
        acc += lrelu(s) * sWd2[j];
    }
    out[bg] = acc;
}

extern "C" void kernel_launch(void* const* d_in, const int* in_sizes, int n_in,
                              void* d_out, int out_size, void* d_ws, size_t ws_size,
                              hipStream_t stream) {
    const float* x     = (const float*)d_in[0];
    const int*   batch = (const int*)  d_in[1];
    const float* We1   = (const float*)d_in[2];
    const float* We2   = (const float*)d_in[3];
    const float* Wg1   = (const float*)d_in[4];
    const float* Wg2   = (const float*)d_in[5];
    const float* Wo1   = (const float*)d_in[6];
    const float* Wo2   = (const float*)d_in[7];
    const float* Wd1   = (const float*)d_in[8];
    const float* Wd2   = (const float*)d_in[9];
    float* out = (float*)d_out;

    // ws layout: [x_aggr B*5][pooled B*32][g_contrib B*40][xe bf16 planar 5*N]
    float* x_aggr    = (float*)d_ws;
    float* pooled    = x_aggr + NUM_GRAPHS * 5;
    float* g_contrib = pooled + NUM_GRAPHS * 32;
    size_t head_bytes = (size_t)NUM_GRAPHS * (5 + 32 + HID) * sizeof(float);
    unsigned short* xe_ws = (unsigned short*)((char*)d_ws + head_bytes);
    size_t need = head_bytes + (size_t)N_POINTS * 5 * sizeof(unsigned short);
    int use_xe = (ws_size >= need) ? 1 : 0;

    hipMemsetAsync(d_ws, 0, (size_t)NUM_GRAPHS * (5 + 32) * sizeof(float), stream);

    int gblk = (NUM_GRAPHS + 255) / 256;
    k_emb_aggr<<<NT_A, 256, 0, stream>>>(x, batch, We1, We2, x_aggr, xe_ws, use_xe);
    k_global <<<gblk, 256, 0, stream>>>(x_aggr, Wg1, Wg2, Wo1, g_contrib);
    k_out_pool<<<NB_C, 256, 0, stream>>>(x, batch, We1, We2, Wo1, Wo2, g_contrib,
                                         xe_ws, use_xe, pooled);
    k_disc   <<<gblk, 256, 0, stream>>>(pooled, Wd1, Wd2, out);
}

// Round 12
// 194.625 us; speedup vs baseline: 4.1182x; 1.0213x over previous
//
#include <hip/hip_runtime.h>
#include <hip/hip_bf16.h>

#define N_POINTS   2000000
#define NUM_GRAPHS 16384
#define HID        40
#define SLOPE      0.01f

// Pass A tiling: 256 pts/tile, grid-stride over 7813 tiles with 2048 blocks
#define TILE_A     256
#define NT_A       ((N_POINTS + TILE_A - 1) / TILE_A)   // 7813
#define NB_A       2048
#define XESA       288    // dwords per xeT channel row (8 chunks x 36; padidx max 283)

// Pass C tiling: 256 pts/tile, grid-stride, wave-private regions + ONE barrier/tile
#define TILE       256
#define NTILES     ((N_POINTS + TILE - 1) / TILE)       // 7813
#define AROW       20     // dwords per bf16 A-staging row (40 bf16)
#define XOS        68     // per-wave xoT stride in dwords: [ch][64 pts + 4 pad]
#define WREG       (32 * XOS)   // 2176 dwords = 8704 B per-wave LDS region
#define NB_C       1024   // R11: 2048 regressed (WRITE 21->29MB, +3us) -> reverted

// LEDGER (cross-round, do not relearn):
//  - PHANTOM-TRAFFIC DISEASE (R1,R3,R6,R7,R9,R10): kernels with per-graph
//    variable-trip nested outer loops (graph-owned structure) produce GB-scale
//    scratch-like FETCH/WRITE regardless of emb-body variant, at VGPR 64 AND 128.
//    The SAME bodies in flat grid-stride structure (R0,R2,R4,R5) are clean.
//    DO NOT reintroduce graph-owned loops. CANARY: WRITE_SIZE >> real stores.
//  - R2: pooled atomics need temporally-clustered reduce phases or L2 write-
//    combining dies (WRITE 21->303MB). Keep pass C's per-tile barrier.
//  - R11: k_out_pool grid 2048 also hurt combining (21->29MB, 61.4->64.5us).
//    Grid 1024 is the proven point.
//  - R4: register prefetch of batch/xe = neutral.
//  - R5 champion: 189.7us; k_out_pool 61.4us / VGPR 64 / WRITE 20.9MB.
//  - R12 (this): pass A grid-stride-ified (2048 blocks, ~3.8 tiles each) to
//    amortize per-block weight preload + retire overhead; body byte-identical;
//    loop shape copied from pass C (proven clean with this same emb body).

typedef __attribute__((ext_vector_type(8))) short short8;
typedef __attribute__((ext_vector_type(4))) float fx4;

__device__ __forceinline__ float lrelu(float v) { return v > 0.f ? v : SLOPE * v; }
__device__ __forceinline__ int padidx(int p) { return p + ((p >> 5) << 2); }  // +4 dwords per 32-chunk
__device__ __forceinline__ unsigned short f2bf(float f) {
    __hip_bfloat16 h = __float2bfloat16(f);
    return *(unsigned short*)&h;
}
__device__ __forceinline__ float bf2f(unsigned short u) {
    unsigned int v = ((unsigned int)u) << 16;
    return __uint_as_float(v);
}

// ---------------- Pass A: emb FFN (1 pt/thread, h[40]/j4 body) + transpose-reduce + xe cache ----------------
// R12: grid-stride outer loop (pass-C idiom); per-tile body is R5-proven verbatim.
__global__ __launch_bounds__(256, 4) void k_emb_aggr(
    const float* __restrict__ x, const int* __restrict__ batch,
    const float* __restrict__ We1, const float* __restrict__ We2,
    float* __restrict__ x_aggr, unsigned short* __restrict__ xe_out, int use_xe)
{
    __shared__ __align__(16) float sWe1[3 * HID];
    __shared__ __align__(16) float sWe2T[5 * HID];          // [c][j]
    __shared__ __align__(16) float xeT[5 * XESA];           // chunk-padded
    __shared__ __align__(16) int   sbp[XESA];

    int tid = threadIdx.x;
    for (int k = tid; k < 3 * HID; k += 256) sWe1[k] = We1[k];
    for (int k = tid; k < 5 * HID; k += 256) sWe2T[k] = We2[(k % HID) * 5 + k / HID];
    __syncthreads();

    for (int t = blockIdx.x; t < NT_A; t += gridDim.x) {
        int p = t * TILE_A + tid;
        bool v = p < N_POINTS;
        int ic = v ? p : (N_POINTS - 1);
        float x0 = x[ic * 3 + 0], x1 = x[ic * 3 + 1], x2 = x[ic * 3 + 2];
        int b = v ? batch[ic] : -1;
        sbp[padidx(tid)] = b;

        float h[HID];
        const float4* W1r = (const float4*)sWe1;
#pragma unroll
        for (int j4 = 0; j4 < HID / 4; ++j4) {
            float4 wa = W1r[j4], wb = W1r[10 + j4], wc = W1r[20 + j4];
            float wav[4] = {wa.x, wa.y, wa.z, wa.w};
            float wbv[4] = {wb.x, wb.y, wb.z, wb.w};
            float wcv[4] = {wc.x, wc.y, wc.z, wc.w};
#pragma unroll
            for (int k = 0; k < 4; ++k)
                h[j4 * 4 + k] = lrelu(x0 * wav[k] + x1 * wbv[k] + x2 * wcv[k]);
        }

#pragma unroll
        for (int c = 0; c < 5; ++c) {
            const float4* wr = (const float4*)&sWe2T[c * HID];
            float s = 0.f;
#pragma unroll
            for (int j4 = 0; j4 < HID / 4; ++j4) {
                float4 w = wr[j4];
                s += h[j4 * 4 + 0] * w.x + h[j4 * 4 + 1] * w.y + h[j4 * 4 + 2] * w.z + h[j4 * 4 + 3] * w.w;
            }
            float e = v ? lrelu(s) : 0.f;
            xeT[c * XESA + padidx(tid)] = e;
            if (use_xe && v) xe_out[(size_t)c * N_POINTS + p] = f2bf(e);
        }
        __syncthreads();   // xeT/sbp ready for reduce

        if (tid < 40) {
            int ch = tid >> 3, chunk = tid & 7;
            float acc = 0.f;
            int cur = sbp[chunk * 36];
#pragma unroll
            for (int g = 0; g < 8; ++g) {
                float4 v4 = *(const float4*)&xeT[ch * XESA + chunk * 36 + g * 4];
                int4   n4 = *(const int4*)&sbp[chunk * 36 + g * 4];
                float vv[4] = {v4.x, v4.y, v4.z, v4.w};
                int   nn[4] = {n4.x, n4.y, n4.z, n4.w};
#pragma unroll
                for (int k = 0; k < 4; ++k) {
                    if (nn[k] != cur) {
                        if (cur >= 0) atomicAdd(&x_aggr[cur * 5 + ch], acc);
                        cur = nn[k];
                        acc = vv[k];
                    } else {
                        acc += vv[k];
                    }
                }
            }
            if (cur >= 0) atomicAdd(&x_aggr[cur * 5 + ch], acc);
        }
        __syncthreads();   // reduce reads done -> next tile may restage xeT/sbp
    }
}

// ---------------- Pass B: per-graph global FFN + fold into W_out1 rows 5..8 ----------------
__global__ __launch_bounds__(256) void k_global(
    const float* __restrict__ x_aggr,
    const float* __restrict__ Wg1, const float* __restrict__ Wg2,
    const float* __restrict__ Wo1,
    float* __restrict__ g_contrib)
{
    __shared__ float sWg1[5 * HID];
    __shared__ float sWg2[HID * 4];
    __shared__ float sWo1g[4 * HID];
    for (int k = threadIdx.x; k < 5 * HID; k += 256) sWg1[k] = Wg1[k];
    for (int k = threadIdx.x; k < HID * 4; k += 256) sWg2[k] = Wg2[k];
    for (int k = threadIdx.x; k < 4 * HID; k += 256) sWo1g[k] = Wo1[5 * HID + k];
    __syncthreads();

    int bg = blockIdx.x * 256 + threadIdx.x;
    if (bg >= NUM_GRAPHS) return;

    float a[5];
#pragma unroll
    for (int c = 0; c < 5; ++c) a[c] = x_aggr[bg * 5 + c];

    float h[HID];
#pragma unroll
    for (int j = 0; j < HID; ++j) {
        float s = 0.f;
#pragma unroll
        for (int c = 0; c < 5; ++c) s += a[c] * sWg1[c * HID + j];
        h[j] = lrelu(s);
    }
    float g[4];
#pragma unroll
    for (int c = 0; c < 4; ++c) {
        float s = 0.f;
#pragma unroll
        for (int j = 0; j < HID; ++j) s += h[j] * sWg2[j * 4 + c];
        g[c] = lrelu(s);
    }
#pragma unroll
    for (int j = 0; j < HID; ++j) {
        float s = 0.f;
#pragma unroll
        for (int c = 0; c < 4; ++c) s += g[c] * sWo1g[c * HID + j];
        g_contrib[bg * HID + j] = s;
    }
}

// ---------------- Pass C: wave-private LDS regions + ONE barrier per tile ----------------
// R5-proven verbatim, grid 1024.
__global__ __launch_bounds__(256, 4) void k_out_pool(
    const float* __restrict__ x, const int* __restrict__ batch,
    const float* __restrict__ We1, const float* __restrict__ We2,
    const float* __restrict__ Wo1, const float* __restrict__ Wo2,
    const float* __restrict__ g_contrib,
    const unsigned short* __restrict__ xe_in, int use_xe,
    float* __restrict__ pooled)
{
    __shared__ __align__(16) unsigned int uLds[4 * WREG];
    __shared__ __align__(16) int sb[TILE];
    __shared__ float sWe1[3 * HID];
    __shared__ float sWe2T[5 * HID];
    __shared__ float sWo1[5 * HID];

    int tid = threadIdx.x;
    for (int k = tid; k < 3 * HID; k += 256) sWe1[k] = We1[k];
    for (int k = tid; k < 5 * HID; k += 256) sWe2T[k] = We2[(k % HID) * 5 + k / HID];
    for (int k = tid; k < 5 * HID; k += 256) sWo1[k] = Wo1[k];

    int wid = tid >> 6, lane = tid & 63;
    int l16 = lane & 15, quad = lane >> 4;
    unsigned int* wreg = &uLds[wid * WREG];

    short8 bfrag[2][2];
#pragma unroll
    for (int nt = 0; nt < 2; ++nt) {
#pragma unroll
        for (int ks = 0; ks < 2; ++ks) {
#pragma unroll
            for (int j = 0; j < 8; ++j) {
                int kk = ks * 32 + quad * 8 + j;
                float w = (kk < HID) ? Wo2[kk * 32 + nt * 16 + l16] : 0.f;
                bfrag[nt][ks][j] = (short)f2bf(w);
            }
        }
    }
    short8 zfrag = {0, 0, 0, 0, 0, 0, 0, 0};
    __syncthreads();   // weights visible

    for (int t = blockIdx.x; t < NTILES; t += gridDim.x) {
        int i = t * TILE + tid;
        bool v = i < N_POINTS;
        int ic = v ? i : (N_POINTS - 1);
        int b = v ? batch[ic] : -1;
        sb[tid] = b;

        float xe[5];
        if (use_xe) {
#pragma unroll
            for (int c = 0; c < 5; ++c) xe[c] = bf2f(xe_in[(size_t)c * N_POINTS + ic]);
        } else {
            float x0 = x[ic * 3 + 0], x1 = x[ic * 3 + 1], x2 = x[ic * 3 + 2];
            float h[HID];
            const float4* W1r = (const float4*)sWe1;
#pragma unroll
            for (int j4 = 0; j4 < HID / 4; ++j4) {
                float4 wa = W1r[j4], wb = W1r[10 + j4], wc = W1r[20 + j4];
                float wav[4] = {wa.x, wa.y, wa.z, wa.w};
                float wbv[4] = {wb.x, wb.y, wb.z, wb.w};
                float wcv[4] = {wc.x, wc.y, wc.z, wc.w};
#pragma unroll
                for (int k = 0; k < 4; ++k)
                    h[j4 * 4 + k] = lrelu(x0 * wav[k] + x1 * wbv[k] + x2 * wcv[k]);
            }
#pragma unroll
            for (int c = 0; c < 5; ++c) {
                const float4* wr = (const float4*)&sWe2T[c * HID];
                float s = 0.f;
#pragma unroll
                for (int j4 = 0; j4 < HID / 4; ++j4) {
                    float4 w = wr[j4];
                    s += h[j4 * 4 + 0] * w.x + h[j4 * 4 + 1] * w.y + h[j4 * 4 + 2] * w.z + h[j4 * 4 + 3] * w.w;
                }
                xe[c] = lrelu(s);
            }
        }

        const float4* gc4 = (const float4*)(g_contrib + (size_t)(b >= 0 ? b : 0) * HID);
        unsigned int* row = &wreg[lane * AROW];
#pragma unroll
        for (int j4 = 0; j4 < HID / 4; ++j4) {
            float4 g = gc4[j4];
            float sv[4] = {g.x, g.y, g.z, g.w};
#pragma unroll
            for (int c = 0; c < 5; ++c) {
                float4 w = ((const float4*)&sWo1[c * HID])[j4];
                float wvv[4] = {w.x, w.y, w.z, w.w};
#pragma unroll
                for (int k = 0; k < 4; ++k) sv[k] += xe[c] * wvv[k];
            }
            __hip_bfloat162 q0 = __float22bfloat162_rn(make_float2(lrelu(sv[0]), lrelu(sv[1])));
            __hip_bfloat162 q1 = __float22bfloat162_rn(make_float2(lrelu(sv[2]), lrelu(sv[3])));
            uint2 u;
            u.x = *(unsigned int*)&q0; u.y = *(unsigned int*)&q1;
            *(uint2*)(row + j4 * 2) = u;
        }

        fx4 xov[4][2];
#pragma unroll
        for (int m = 0; m < 4; ++m) {
            const unsigned int* arow = &wreg[(m * 16 + l16) * AROW];
            short8 a0 = *(const short8*)(arow + quad * 4);
            short8 a1 = (quad == 0) ? *(const short8*)(arow + 16) : zfrag;
#pragma unroll
            for (int nt = 0; nt < 2; ++nt) {
                fx4 acc = {0.f, 0.f, 0.f, 0.f};
                acc = __builtin_amdgcn_mfma_f32_16x16x32_bf16(a0, bfrag[nt][0], acc, 0, 0, 0);
                acc = __builtin_amdgcn_mfma_f32_16x16x32_bf16(a1, bfrag[nt][1], acc, 0, 0, 0);
#pragma unroll
                for (int r = 0; r < 4; ++r) acc[r] = lrelu(acc[r]);
                xov[m][nt] = acc;
            }
        }

        float* xoT = (float*)wreg;
#pragma unroll
        for (int m = 0; m < 4; ++m) {
#pragma unroll
            for (int nt = 0; nt < 2; ++nt) {
                int ch = nt * 16 + l16;
                *(fx4*)&xoT[ch * XOS + m * 16 + quad * 4] = xov[m][nt];
            }
        }

        {
            int ch = lane & 31, half = lane >> 5;
            int pbase = half * 32;
            const int* sbw = &sb[wid * 64];
            float acc = 0.f;
            int cur = sbw[pbase];
#pragma unroll
            for (int g = 0; g < 8; ++g) {
                float4 v4 = *(const float4*)&xoT[ch * XOS + pbase + g * 4];
                int4   n4 = *(const int4*)&sbw[pbase + g * 4];
                float vv[4] = {v4.x, v4.y, v4.z, v4.w};
                int   nn[4] = {n4.x, n4.y, n4.z, n4.w};
#pragma unroll
                for (int k = 0; k < 4; ++k) {
                    if (nn[k] != cur) {
                        if (cur >= 0) atomicAdd(&pooled[cur * 32 + ch], acc);
                        cur = nn[k];
                        acc = vv[k];
                    } else {
                        acc += vv[k];
                    }
                }
            }
            if (cur >= 0) atomicAdd(&pooled[cur * 32 + ch], acc);
        }

        __syncthreads();   // rate-match waves once per tile (atomic write-combining)
    }
}

// ---------------- Pass D: disc head per graph ----------------
__global__ __launch_bounds__(256) void k_disc(
    const float* __restrict__ pooled,
    const float* __restrict__ Wd1, const float* __restrict__ Wd2,
    float* __restrict__ out)
{
    __shared__ float sWd1T[HID * 32];  // [j][c]
    __shared__ float sWd2[HID];
    for (int k = threadIdx.x; k < 32 * HID; k += 256) sWd1T[k] = Wd1[(k % 32) * HID + k / 32];
    for (int k = threadIdx.x; k < HID; k += 256) sWd2[k] = Wd2[k];
    __syncthreads();

    int bg = blockIdx.x * 256 + threadIdx.x;
    if (bg >= NUM_GRAPHS) return;

    float p[32];
    const float4* pp = (const float4*)(pooled + (size_t)bg * 32);
#pragma unroll
    for (int c4 = 0; c4 < 8; ++c4) {
        float4 vv = pp[c4];
        p[c4 * 4 + 0] = vv.x; p[c4 * 4 + 1] = vv.y; p[c4 * 4 + 2] = vv.z; p[c4 * 4 + 3] = vv.w;
    }

    float acc = 0.f;
#pragma unroll
    for (int j = 0; j < HID; ++j) {
        const float4* wr = (const float4*)&sWd1T[j * 32];
        float s = 0.f;
#pragma unroll
        for (int c4 = 0; c4 < 8; ++c4) {
            float4 w = wr[c4];
            s += p[c4 * 4 + 0] * w.x + p[c4 * 4 + 1] * w.y + p[c4 * 4 + 2] * w.z + p[c4 * 4 + 3] * w.w;
        }
        acc += lrelu(s) * sWd2[j];
    }
    out[bg] = acc;
}

extern "C" void kernel_launch(void* const* d_in, const int* in_sizes, int n_in,
                              void* d_out, int out_size, void* d_ws, size_t ws_size,
                              hipStream_t stream) {
    const float* x     = (const float*)d_in[0];
    const int*   batch = (const int*)  d_in[1];
    const float* We1   = (const float*)d_in[2];
    const float* We2   = (const float*)d_in[3];
    const float* Wg1   = (const float*)d_in[4];
    const float* Wg2   = (const float*)d_in[5];
    const float* Wo1   = (const float*)d_in[6];
    const float* Wo2   = (const float*)d_in[7];
    const float* Wd1   = (const float*)d_in[8];
    const float* Wd2   = (const float*)d_in[9];
    float* out = (float*)d_out;

    // ws layout: [x_aggr B*5][pooled B*32][g_contrib B*40][xe bf16 planar 5*N]
    float* x_aggr    = (float*)d_ws;
    float* pooled    = x_aggr + NUM_GRAPHS * 5;
    float* g_contrib = pooled + NUM_GRAPHS * 32;
    size_t head_bytes = (size_t)NUM_GRAPHS * (5 + 32 + HID) * sizeof(float);
    unsigned short* xe_ws = (unsigned short*)((char*)d_ws + head_bytes);
    size_t need = head_bytes + (size_t)N_POINTS * 5 * sizeof(unsigned short);
    int use_xe = (ws_size >= need) ? 1 : 0;

    hipMemsetAsync(d_ws, 0, (size_t)NUM_GRAPHS * (5 + 32) * sizeof(float), stream);

    int gblk = (NUM_GRAPHS + 255) / 256;
    k_emb_aggr<<<NB_A, 256, 0, stream>>>(x, batch, We1, We2, x_aggr, xe_ws, use_xe);
    k_global <<<gblk, 256, 0, stream>>>(x_aggr, Wg1, Wg2, Wo1, g_contrib);
    k_out_pool<<<NB_C, 256, 0, stream>>>(x, batch, We1, We2, Wo1, Wo2, g_contrib,
                                         xe_ws, use_xe, pooled);
    k_disc   <<<gblk, 256, 0, stream>>>(pooled, Wd1, Wd2, out);
}